// Round 2
// baseline (1434.463 us; speedup 1.0000x reference)
//
#include <hip/hip_runtime.h>
#include <math.h>

#define C 64
#define NHEADS 4
#define DH 16
#define NN 262144   // H*W
#define NB 2
#define EPS 1e-12f

// ---------------- K1: per-batch partial Gram matrices ----------------
// grid (PB, NB), 256 threads. Block covers ntiles*128 cols; writes its own
// 64x64 partial (no atomics). LDS tile: row c (128 floats), quad q stored at
// (q ^ ((c>>3)&7)) -> all b128 LDS reads/writes bank-conflict-free.
__global__ __launch_bounds__(256, 2) void gram_kernel(const float* __restrict__ x,
                                                      float* __restrict__ Gc,
                                                      int PB, int ntiles) {
  __shared__ float lds[C * 128];
  const int b = blockIdx.y;
  const int chunk = blockIdx.x;
  const float* xb = x + (size_t)b * C * NN;
  const int t = threadIdx.x;
  const int wid = t >> 6;
  const int lane = t & 63;
  const int ly = lane >> 3, lx = lane & 7;

  float acc[8][8];
#pragma unroll
  for (int a = 0; a < 8; ++a)
#pragma unroll
    for (int bb = 0; bb < 8; ++bb) acc[a][bb] = 0.f;

  for (int tile = 0; tile < ntiles; ++tile) {
    const int j0 = (chunk * ntiles + tile) * 128;
    __syncthreads();
#pragma unroll
    for (int i = 0; i < 8; ++i) {
      const int idx = i * 256 + t;
      const int c = idx >> 5, jq = idx & 31;
      const float4 v = *reinterpret_cast<const float4*>(xb + (size_t)c * NN + j0 + jq * 4);
      const int sq = jq ^ ((c >> 3) & 7);
      *reinterpret_cast<float4*>(&lds[c * 128 + sq * 4]) = v;
    }
    __syncthreads();
    // wave wid handles quads [8*wid, 8*wid+8)
#pragma unroll
    for (int qi = 0; qi < 8; ++qi) {
      const int q = wid * 8 + qi;
      float4 f1[8], f2[8];
#pragma unroll
      for (int a = 0; a < 8; ++a) {
        const int c1 = ly * 8 + a;
        f1[a] = *reinterpret_cast<const float4*>(&lds[c1 * 128 + (((q ^ ly) & 31) << 2)]);
        const int c2 = lx * 8 + a;
        f2[a] = *reinterpret_cast<const float4*>(&lds[c2 * 128 + (((q ^ lx) & 31) << 2)]);
      }
#pragma unroll
      for (int a = 0; a < 8; ++a)
#pragma unroll
        for (int bb = 0; bb < 8; ++bb)
          acc[a][bb] += f1[a].x * f2[bb].x + f1[a].y * f2[bb].y +
                        f1[a].z * f2[bb].z + f1[a].w * f2[bb].w;
    }
  }
  // cross-wave reduce into lds[0..4096)
  __syncthreads();
  for (int w = 0; w < 4; ++w) {
    if (wid == w) {
#pragma unroll
      for (int a = 0; a < 8; ++a)
#pragma unroll
        for (int bb = 0; bb < 8; ++bb) {
          const int r = ly * 8 + a, cg = lx * 8 + bb;
          if (w == 0) lds[r * 64 + cg] = acc[a][bb];
          else        lds[r * 64 + cg] += acc[a][bb];
        }
    }
    __syncthreads();
  }
  float* g = Gc + ((size_t)b * PB + chunk) * 4096;
  for (int i = t; i < 4096; i += 256) g[i] = lds[i];
}

// ---------------- K1b: tree-reduce the PB partials -> G[b][4096] ----------------
// grid (64, NB), 256 threads. Block g handles elements [g*64, g*64+64).
__global__ __launch_bounds__(256) void reduce_kernel(const float* __restrict__ Gc,
                                                     float* __restrict__ G, int PB) {
  __shared__ float s[4][64];
  const int b = blockIdx.y;
  const int g = blockIdx.x;
  const int t = threadIdx.x;
  const int e = g * 64 + (t & 63);
  const int chunk = t >> 6;
  float sum = 0.f;
  for (int p = chunk; p < PB; p += 4)
    sum += Gc[((size_t)b * PB + p) * 4096 + e];
  s[chunk][t & 63] = sum;
  __syncthreads();
  if (t < 64) G[(size_t)b * 4096 + g * 64 + t] = s[0][t] + s[1][t] + s[2][t] + s[3][t];
}

// ---------------- K2: all attention math on 64x64 matrices ----------------
// grid 2 (one block per batch). Produces E[b] = Wp * BD(softmax(attn)) * Wv + I.
__global__ __launch_bounds__(256) void attn_kernel(const float* __restrict__ G,
    const float* __restrict__ Wq, const float* __restrict__ Wk,
    const float* __restrict__ Wv, const float* __restrict__ Wp,
    const float* __restrict__ rescale, float* __restrict__ E) {
  __shared__ float Gs[4096], GQt[4096], GKt[4096], T[4096];
  __shared__ float attnw[64][DH];
  __shared__ float nq[64], nk[64];
  const int b = blockIdx.x;
  const int t = threadIdx.x;

  for (int i = t; i < 4096; i += 256) Gs[i] = G[(size_t)b * 4096 + i];
  __syncthreads();
  // GQt[c][e] = (G Wq^T)[c][e],  GKt[c][e] = (G Wk^T)[c][e]
  for (int i = t; i < 4096; i += 256) {
    const int c = i >> 6, e = i & 63;
    float sq_ = 0.f, sk_ = 0.f;
    for (int c2 = 0; c2 < 64; ++c2) {
      const float g = Gs[c * 64 + c2];
      sq_ += g * Wq[e * 64 + c2];
      sk_ += g * Wk[e * 64 + c2];
    }
    GQt[c * 64 + e] = sq_;
    GKt[c * 64 + e] = sk_;
  }
  __syncthreads();
  if (t < 64) {
    float s = 0.f;
    for (int c2 = 0; c2 < 64; ++c2) s += Wq[t * 64 + c2] * GQt[c2 * 64 + t];
    nq[t] = sqrtf(fmaxf(s, 0.f));
  } else if (t < 128) {
    const int d = t - 64;
    float s = 0.f;
    for (int c2 = 0; c2 < 64; ++c2) s += Wk[d * 64 + c2] * GKt[c2 * 64 + d];
    nk[d] = sqrtf(fmaxf(s, 0.f));
  }
  __syncthreads();
  // per attention row (64 rows): logits -> softmax
  if (t < 64) {
    const int h = t >> 4;
    const float rs = rescale[h];
    const float nkd = fmaxf(nk[t], EPS);
    float logits[DH];
    float mx = -1e30f;
    for (int ee = 0; ee < DH; ++ee) {
      const int e = h * DH + ee;
      float num = 0.f;
      for (int c2 = 0; c2 < 64; ++c2) num += Wk[t * 64 + c2] * GQt[c2 * 64 + e];
      const float l = num / (nkd * fmaxf(nq[e], EPS)) * rs;
      logits[ee] = l;
      mx = fmaxf(mx, l);
    }
    float sum = 0.f;
    for (int ee = 0; ee < DH; ++ee) { const float p = expf(logits[ee] - mx); logits[ee] = p; sum += p; }
    const float inv = 1.f / sum;
    for (int ee = 0; ee < DH; ++ee) attnw[t][ee] = logits[ee] * inv;
  }
  __syncthreads();
  // T = BD(attn) * Wv
  for (int i = t; i < 4096; i += 256) {
    const int r = i >> 6, c = i & 63;
    const int h = r >> 4;
    float s = 0.f;
    for (int e = 0; e < DH; ++e) s += attnw[r][e] * Wv[(h * DH + e) * 64 + c];
    T[i] = s;
  }
  __syncthreads();
  // E = Wp * T + I
  for (int i = t; i < 4096; i += 256) {
    const int r = i >> 6, c = i & 63;
    float s = (r == c) ? 1.f : 0.f;
    for (int m = 0; m < 64; ++m) s += Wp[r * 64 + m] * T[m * 64 + c];
    E[(size_t)b * 4096 + i] = s;
  }
}

// ---------------- K3: out = E * x + bp  (E already includes +I) ----------------
// grid 1024 (512/batch), 256 threads, 4 tiles x 128 cols per block.
__global__ __launch_bounds__(256, 2) void apply_kernel(const float* __restrict__ x,
    const float* __restrict__ E, const float* __restrict__ bp,
    float* __restrict__ out) {
  __shared__ float xt[C * 128];
  __shared__ float Mt[C * 68];   // Mt[k][c] = M[c][k], stride 68
  const int blk = blockIdx.x;
  const int b = blk >> 9;
  const int chunk = blk & 511;
  const float* xb = x + (size_t)b * C * NN;
  float* ob = out + (size_t)b * C * NN;
  const int t = threadIdx.x;
  const int wid = t >> 6, lane = t & 63;
  const int ly = lane >> 3, lx = lane & 7;

  for (int i = t; i < 4096; i += 256) {
    const int k = i >> 6, c = i & 63;
    Mt[k * 68 + c] = E[(size_t)b * 4096 + c * 64 + k];
  }

  for (int tile = 0; tile < 4; ++tile) {
    const int j0 = chunk * 512 + tile * 128;
    __syncthreads();
#pragma unroll
    for (int i = 0; i < 8; ++i) {
      const int idx = i * 256 + t;
      const int c = idx >> 5, jq = idx & 31;
      const float4 v = *reinterpret_cast<const float4*>(xb + (size_t)c * NN + j0 + jq * 4);
      const int sq = jq ^ ((c >> 3) & 7);
      *reinterpret_cast<float4*>(&xt[c * 128 + sq * 4]) = v;
    }
    __syncthreads();
    const int qL = wid * 8 + lx;  // this lane's quad within the 128-col tile
    float acc[8][4];
#pragma unroll
    for (int a = 0; a < 8; ++a)
#pragma unroll
      for (int r = 0; r < 4; ++r) acc[a][r] = 0.f;
#pragma unroll 4
    for (int k = 0; k < 64; ++k) {
      const float4 m0 = *reinterpret_cast<const float4*>(&Mt[k * 68 + ly * 8]);
      const float4 m1 = *reinterpret_cast<const float4*>(&Mt[k * 68 + ly * 8 + 4]);
      const float4 xv = *reinterpret_cast<const float4*>(&xt[k * 128 + ((qL ^ ((k >> 3) & 7)) << 2)]);
      const float mv[8] = {m0.x, m0.y, m0.z, m0.w, m1.x, m1.y, m1.z, m1.w};
#pragma unroll
      for (int a = 0; a < 8; ++a) {
        acc[a][0] += mv[a] * xv.x;
        acc[a][1] += mv[a] * xv.y;
        acc[a][2] += mv[a] * xv.z;
        acc[a][3] += mv[a] * xv.w;
      }
    }
#pragma unroll
    for (int a = 0; a < 8; ++a) {
      const int c1 = ly * 8 + a;
      const float bias = bp[c1];
      float4 o4;
      o4.x = acc[a][0] + bias;
      o4.y = acc[a][1] + bias;
      o4.z = acc[a][2] + bias;
      o4.w = acc[a][3] + bias;
      *reinterpret_cast<float4*>(&ob[(size_t)c1 * NN + j0 + qL * 4]) = o4;
    }
  }
}

extern "C" void kernel_launch(void* const* d_in, const int* in_sizes, int n_in,
                              void* d_out, int out_size, void* d_ws, size_t ws_size,
                              hipStream_t stream) {
  const float* x       = (const float*)d_in[0];
  const float* Wq      = (const float*)d_in[1];
  const float* Wk      = (const float*)d_in[2];
  const float* Wv      = (const float*)d_in[3];
  const float* Wp      = (const float*)d_in[4];
  const float* bp      = (const float*)d_in[5];
  const float* rescale = (const float*)d_in[6];
  float* out = (float*)d_out;

  // pick partials-per-batch PB so scratch fits: NB*PB*16KB + G(32KB) + E(32KB)
  int PB = 256;
  while (PB > 8 && (size_t)NB * PB * 4096 * sizeof(float) + 2 * (size_t)NB * 4096 * sizeof(float) > ws_size)
    PB >>= 1;
  const int ntiles = 2048 / PB;

  float* Gc = (float*)d_ws;                         // NB*PB*4096 floats
  float* G  = Gc + (size_t)NB * PB * 4096;          // NB*4096
  float* E  = G + (size_t)NB * 4096;                // NB*4096

  gram_kernel<<<dim3(PB, NB), dim3(256), 0, stream>>>(x, Gc, PB, ntiles);
  reduce_kernel<<<dim3(64, NB), dim3(256), 0, stream>>>(Gc, G, PB);
  attn_kernel<<<dim3(NB), dim3(256), 0, stream>>>(G, Wq, Wk, Wv, Wp, rescale, E);
  apply_kernel<<<dim3(1024), dim3(256), 0, stream>>>(x, E, bp, out);
}

// Round 3
// 754.749 us; speedup vs baseline: 1.9006x; 1.9006x over previous
//
#include <hip/hip_runtime.h>
#include <math.h>

#define C 64
#define NHEADS 4
#define DH 16
#define NN 262144   // H*W
#define NB 2
#define PB 512      // partial Gram blocks per batch
#define NT 4        // 128-col tiles per block
#define EPS 1e-12f

// ---------------- K1: per-batch partial Gram matrices ----------------
// grid (PB, NB), 256 threads. Block covers NT*128 cols; writes its own
// 64x64 partial to d_out scratch (no atomics). LDS tile: row c (128 floats),
// quad q stored at (q ^ ((c>>3)&7)) -> b128 reads/writes conflict-free.
// launch_bounds(256,1): VGPR cap 512 -> must not spill (R2 post-mortem:
// 128-VGPR cap spilled f1/f2 arrays -> 4.3 GB scratch traffic).
__global__ __launch_bounds__(256, 1) void gram_kernel(const float* __restrict__ x,
                                                      float* __restrict__ Gc) {
  __shared__ float lds[C * 128];
  const int b = blockIdx.y;
  const int chunk = blockIdx.x;
  const float* xb = x + (size_t)b * C * NN;
  const int t = threadIdx.x;
  const int wid = t >> 6;
  const int lane = t & 63;
  const int ly = lane >> 3, lx = lane & 7;

  float acc[8][8];
#pragma unroll
  for (int a = 0; a < 8; ++a)
#pragma unroll
    for (int bb = 0; bb < 8; ++bb) acc[a][bb] = 0.f;

  for (int tile = 0; tile < NT; ++tile) {
    const int j0 = (chunk * NT + tile) * 128;
    __syncthreads();
#pragma unroll
    for (int i = 0; i < 8; ++i) {
      const int idx = i * 256 + t;
      const int c = idx >> 5, jq = idx & 31;
      const float4 v = *reinterpret_cast<const float4*>(xb + (size_t)c * NN + j0 + jq * 4);
      const int sq = jq ^ ((c >> 3) & 7);
      *reinterpret_cast<float4*>(&lds[c * 128 + sq * 4]) = v;
    }
    __syncthreads();
    // wave wid handles quads [8*wid, 8*wid+8)
#pragma unroll
    for (int qi = 0; qi < 8; ++qi) {
      const int q = wid * 8 + qi;
      float4 f1[8];
#pragma unroll
      for (int a = 0; a < 8; ++a)
        f1[a] = *reinterpret_cast<const float4*>(&lds[(ly * 8 + a) * 128 + (((q ^ ly) & 31) << 2)]);
#pragma unroll
      for (int bb = 0; bb < 8; ++bb) {
        const float4 f2 = *reinterpret_cast<const float4*>(&lds[(lx * 8 + bb) * 128 + (((q ^ lx) & 31) << 2)]);
#pragma unroll
        for (int a = 0; a < 8; ++a)
          acc[a][bb] += f1[a].x * f2.x + f1[a].y * f2.y + f1[a].z * f2.z + f1[a].w * f2.w;
      }
    }
  }
  // cross-wave reduce into lds[0..4096)
  __syncthreads();
  for (int w = 0; w < 4; ++w) {
    if (wid == w) {
#pragma unroll
      for (int a = 0; a < 8; ++a)
#pragma unroll
        for (int bb = 0; bb < 8; ++bb) {
          const int r = ly * 8 + a, cg = lx * 8 + bb;
          if (w == 0) lds[r * 64 + cg] = acc[a][bb];
          else        lds[r * 64 + cg] += acc[a][bb];
        }
    }
    __syncthreads();
  }
  float* g = Gc + ((size_t)b * PB + chunk) * 4096;
  for (int i = t; i < 4096; i += 256) g[i] = lds[i];
}

// ---------------- K1b: tree-reduce the PB partials -> G[b][4096] ----------------
// grid (64, NB), 256 threads. Block g handles elements [g*64, g*64+64).
__global__ __launch_bounds__(256) void reduce_kernel(const float* __restrict__ Gc,
                                                     float* __restrict__ G) {
  __shared__ float s[4][64];
  const int b = blockIdx.y;
  const int g = blockIdx.x;
  const int t = threadIdx.x;
  const int e = g * 64 + (t & 63);
  const int chunk = t >> 6;
  float sum = 0.f;
  for (int p = chunk; p < PB; p += 4)
    sum += Gc[((size_t)b * PB + p) * 4096 + e];
  s[chunk][t & 63] = sum;
  __syncthreads();
  if (t < 64) G[(size_t)b * 4096 + g * 64 + t] = s[0][t] + s[1][t] + s[2][t] + s[3][t];
}

// ---------------- K2: all attention math on 64x64 matrices ----------------
// grid 2 (one block per batch). Produces E[b] = Wp * BD(softmax(attn)) * Wv + I.
__global__ __launch_bounds__(256) void attn_kernel(const float* __restrict__ G,
    const float* __restrict__ Wq, const float* __restrict__ Wk,
    const float* __restrict__ Wv, const float* __restrict__ Wp,
    const float* __restrict__ rescale, float* __restrict__ E) {
  __shared__ float Gs[4096], GQt[4096], GKt[4096], T[4096];
  __shared__ float attnw[64][DH];
  __shared__ float nq[64], nk[64];
  const int b = blockIdx.x;
  const int t = threadIdx.x;

  for (int i = t; i < 4096; i += 256) Gs[i] = G[(size_t)b * 4096 + i];
  __syncthreads();
  // GQt[c][e] = (G Wq^T)[c][e],  GKt[c][e] = (G Wk^T)[c][e]
  for (int i = t; i < 4096; i += 256) {
    const int c = i >> 6, e = i & 63;
    float sq_ = 0.f, sk_ = 0.f;
    for (int c2 = 0; c2 < 64; ++c2) {
      const float g = Gs[c * 64 + c2];
      sq_ += g * Wq[e * 64 + c2];
      sk_ += g * Wk[e * 64 + c2];
    }
    GQt[c * 64 + e] = sq_;
    GKt[c * 64 + e] = sk_;
  }
  __syncthreads();
  if (t < 64) {
    float s = 0.f;
    for (int c2 = 0; c2 < 64; ++c2) s += Wq[t * 64 + c2] * GQt[c2 * 64 + t];
    nq[t] = sqrtf(fmaxf(s, 0.f));
  } else if (t < 128) {
    const int d = t - 64;
    float s = 0.f;
    for (int c2 = 0; c2 < 64; ++c2) s += Wk[d * 64 + c2] * GKt[c2 * 64 + d];
    nk[d] = sqrtf(fmaxf(s, 0.f));
  }
  __syncthreads();
  // per attention row (64 rows): logits -> softmax
  if (t < 64) {
    const int h = t >> 4;
    const float rs = rescale[h];
    const float nkd = fmaxf(nk[t], EPS);
    float logits[DH];
    float mx = -1e30f;
    for (int ee = 0; ee < DH; ++ee) {
      const int e = h * DH + ee;
      float num = 0.f;
      for (int c2 = 0; c2 < 64; ++c2) num += Wk[t * 64 + c2] * GQt[c2 * 64 + e];
      const float l = num / (nkd * fmaxf(nq[e], EPS)) * rs;
      logits[ee] = l;
      mx = fmaxf(mx, l);
    }
    float sum = 0.f;
    for (int ee = 0; ee < DH; ++ee) { const float p = expf(logits[ee] - mx); logits[ee] = p; sum += p; }
    const float inv = 1.f / sum;
    for (int ee = 0; ee < DH; ++ee) attnw[t][ee] = logits[ee] * inv;
  }
  __syncthreads();
  // T = BD(attn) * Wv
  for (int i = t; i < 4096; i += 256) {
    const int r = i >> 6, c = i & 63;
    const int h = r >> 4;
    float s = 0.f;
    for (int e = 0; e < DH; ++e) s += attnw[r][e] * Wv[(h * DH + e) * 64 + c];
    T[i] = s;
  }
  __syncthreads();
  // E = Wp * T + I
  for (int i = t; i < 4096; i += 256) {
    const int r = i >> 6, c = i & 63;
    float s = (r == c) ? 1.f : 0.f;
    for (int m = 0; m < 64; ++m) s += Wp[r * 64 + m] * T[m * 64 + c];
    E[(size_t)b * 4096 + i] = s;
  }
}

// ---------------- K3: out = E * x + bp  (E already includes +I) ----------------
// grid 1024 (512/batch), 256 threads, 4 tiles x 128 cols per block.
__global__ __launch_bounds__(256, 2) void apply_kernel(const float* __restrict__ x,
    const float* __restrict__ E, const float* __restrict__ bp,
    float* __restrict__ out) {
  __shared__ float xt[C * 128];
  __shared__ float Mt[C * 68];   // Mt[k][c] = M[c][k], stride 68
  const int blk = blockIdx.x;
  const int b = blk >> 9;
  const int chunk = blk & 511;
  const float* xb = x + (size_t)b * C * NN;
  float* ob = out + (size_t)b * C * NN;
  const int t = threadIdx.x;
  const int wid = t >> 6, lane = t & 63;
  const int ly = lane >> 3, lx = lane & 7;

  for (int i = t; i < 4096; i += 256) {
    const int k = i >> 6, c = i & 63;
    Mt[k * 68 + c] = E[(size_t)b * 4096 + c * 64 + k];
  }

  for (int tile = 0; tile < 4; ++tile) {
    const int j0 = chunk * 512 + tile * 128;
    __syncthreads();
#pragma unroll
    for (int i = 0; i < 8; ++i) {
      const int idx = i * 256 + t;
      const int c = idx >> 5, jq = idx & 31;
      const float4 v = *reinterpret_cast<const float4*>(xb + (size_t)c * NN + j0 + jq * 4);
      const int sq = jq ^ ((c >> 3) & 7);
      *reinterpret_cast<float4*>(&xt[c * 128 + sq * 4]) = v;
    }
    __syncthreads();
    const int qL = wid * 8 + lx;  // this lane's quad within the 128-col tile
    float acc[8][4];
#pragma unroll
    for (int a = 0; a < 8; ++a)
#pragma unroll
      for (int r = 0; r < 4; ++r) acc[a][r] = 0.f;
#pragma unroll 4
    for (int k = 0; k < 64; ++k) {
      const float4 m0 = *reinterpret_cast<const float4*>(&Mt[k * 68 + ly * 8]);
      const float4 m1 = *reinterpret_cast<const float4*>(&Mt[k * 68 + ly * 8 + 4]);
      const float4 xv = *reinterpret_cast<const float4*>(&xt[k * 128 + ((qL ^ ((k >> 3) & 7)) << 2)]);
      const float mv[8] = {m0.x, m0.y, m0.z, m0.w, m1.x, m1.y, m1.z, m1.w};
#pragma unroll
      for (int a = 0; a < 8; ++a) {
        acc[a][0] += mv[a] * xv.x;
        acc[a][1] += mv[a] * xv.y;
        acc[a][2] += mv[a] * xv.z;
        acc[a][3] += mv[a] * xv.w;
      }
    }
#pragma unroll
    for (int a = 0; a < 8; ++a) {
      const int c1 = ly * 8 + a;
      const float bias = bp[c1];
      float4 o4;
      o4.x = acc[a][0] + bias;
      o4.y = acc[a][1] + bias;
      o4.z = acc[a][2] + bias;
      o4.w = acc[a][3] + bias;
      *reinterpret_cast<float4*>(&ob[(size_t)c1 * NN + j0 + qL * 4]) = o4;
    }
  }
}

extern "C" void kernel_launch(void* const* d_in, const int* in_sizes, int n_in,
                              void* d_out, int out_size, void* d_ws, size_t ws_size,
                              hipStream_t stream) {
  const float* x       = (const float*)d_in[0];
  const float* Wq      = (const float*)d_in[1];
  const float* Wk      = (const float*)d_in[2];
  const float* Wv      = (const float*)d_in[3];
  const float* Wp      = (const float*)d_in[4];
  const float* bp      = (const float*)d_in[5];
  const float* rescale = (const float*)d_in[6];
  float* out = (float*)d_out;

  // Partial Grams live in d_out (16.8 MB of 128 MB) — K3 fully overwrites
  // d_out afterwards, so this is safe and removes any ws_size dependence.
  float* Gc = out;
  float* G  = (float*)d_ws;              // NB*4096 floats
  float* E  = G + (size_t)NB * 4096;     // NB*4096 floats

  gram_kernel<<<dim3(PB, NB), dim3(256), 0, stream>>>(x, Gc);
  reduce_kernel<<<dim3(64, NB), dim3(256), 0, stream>>>(Gc, G);
  attn_kernel<<<dim3(NB), dim3(256), 0, stream>>>(G, Wq, Wk, Wv, Wp, rescale, E);
  apply_kernel<<<dim3(1024), dim3(256), 0, stream>>>(x, E, bp, out);
}

// Round 4
// 181.563 us; speedup vs baseline: 7.9006x; 4.1570x over previous
//
#include <hip/hip_runtime.h>
#include <math.h>

#define C 64
#define NHEADS 4
#define DH 16
#define NN 262144   // H*W
#define NB 2
#define PB 512      // partial Gram blocks per batch
#define NT 2        // 256-col tiles per block
#define EPS 1e-12f

typedef __attribute__((ext_vector_type(8))) short short8v;     // 8 bf16
typedef __attribute__((ext_vector_type(8))) unsigned short ushort8v;
typedef __attribute__((ext_vector_type(4))) float f32x4;

static __device__ __forceinline__ unsigned short f2bf(float f) {
  union { float f; unsigned int u; } v; v.f = f;
  unsigned int r = v.u + 0x7fffu + ((v.u >> 16) & 1u);   // RNE round to bf16
  return (unsigned short)(r >> 16);
}

// ---------------- K1: per-batch partial Gram via MFMA ----------------
// grid (PB, NB), 256 threads = 4 waves. Block covers NT*256 n-cols.
// LDS tile: bf16 [64][256], 16B slot s of row c stored at (s ^ (c&7)) ->
// staging ds_write_b128 and frag ds_read_b128 both <=2-way (free).
// Wave w owns G tile-pairs (gA,gB) for gA in {2(w>>1),+1}, gB in {2(w&1),+1};
// waves own disjoint 16x16 output tiles -> no cross-wave reduce.
__global__ __launch_bounds__(256, 2) void gram_kernel(const float* __restrict__ x,
                                                      float* __restrict__ Gc) {
  __shared__ unsigned short xs[C * 256];
  const int b = blockIdx.y;
  const int chunk = blockIdx.x;
  const float* xb = x + (size_t)b * C * NN;
  const int t = threadIdx.x;
  const int w = t >> 6, l = t & 63;
  const int lrow = l & 15, lhi = l >> 4;

  const int gA0 = (w >> 1) * 2, gA1 = gA0 + 1;
  const int gB0 = (w & 1) * 2,  gB1 = gB0 + 1;
  const int cA0 = gA0 * 16 + lrow, cA1 = gA1 * 16 + lrow;
  const int cB0 = gB0 * 16 + lrow, cB1 = gB1 * 16 + lrow;

  f32x4 acc0 = {0.f,0.f,0.f,0.f}, acc1 = {0.f,0.f,0.f,0.f};
  f32x4 acc2 = {0.f,0.f,0.f,0.f}, acc3 = {0.f,0.f,0.f,0.f};

  for (int tile = 0; tile < NT; ++tile) {
    const int j0 = (chunk * NT + tile) * 256;
    __syncthreads();
#pragma unroll
    for (int i = 0; i < 8; ++i) {
      const int oi = i * 256 + t;
      const int c = oi >> 5, oct = oi & 31;          // 32 octets (8 bf16) per row
      const float* src = xb + (size_t)c * NN + j0 + oct * 8;
      const float4 v0 = *reinterpret_cast<const float4*>(src);
      const float4 v1 = *reinterpret_cast<const float4*>(src + 4);
      ushort8v pk;
      pk[0] = f2bf(v0.x); pk[1] = f2bf(v0.y); pk[2] = f2bf(v0.z); pk[3] = f2bf(v0.w);
      pk[4] = f2bf(v1.x); pk[5] = f2bf(v1.y); pk[6] = f2bf(v1.z); pk[7] = f2bf(v1.w);
      *reinterpret_cast<ushort8v*>(&xs[c * 256 + ((oct ^ (c & 7)) << 3)]) = pk;
    }
    __syncthreads();
#pragma unroll
    for (int s = 0; s < 8; ++s) {
      const int o = s * 4 + lhi;                     // 16B slot holding k=s*32+lhi*8..+7
      const short8v fA0 = *reinterpret_cast<const short8v*>(&xs[cA0 * 256 + ((o ^ (cA0 & 7)) << 3)]);
      const short8v fA1 = *reinterpret_cast<const short8v*>(&xs[cA1 * 256 + ((o ^ (cA1 & 7)) << 3)]);
      const short8v fB0 = *reinterpret_cast<const short8v*>(&xs[cB0 * 256 + ((o ^ (cB0 & 7)) << 3)]);
      const short8v fB1 = *reinterpret_cast<const short8v*>(&xs[cB1 * 256 + ((o ^ (cB1 & 7)) << 3)]);
      acc0 = __builtin_amdgcn_mfma_f32_16x16x32_bf16(fA0, fB0, acc0, 0, 0, 0);
      acc1 = __builtin_amdgcn_mfma_f32_16x16x32_bf16(fA0, fB1, acc1, 0, 0, 0);
      acc2 = __builtin_amdgcn_mfma_f32_16x16x32_bf16(fA1, fB0, acc2, 0, 0, 0);
      acc3 = __builtin_amdgcn_mfma_f32_16x16x32_bf16(fA1, fB1, acc3, 0, 0, 0);
    }
  }
  // C/D layout (m89-verified): col = lane&15, row = (lane>>4)*4 + reg
  float* g = Gc + ((size_t)b * PB + chunk) * 4096;
#pragma unroll
  for (int r = 0; r < 4; ++r) {
    const int row = lhi * 4 + r;
    g[(gA0 * 16 + row) * 64 + gB0 * 16 + lrow] = acc0[r];
    g[(gA0 * 16 + row) * 64 + gB1 * 16 + lrow] = acc1[r];
    g[(gA1 * 16 + row) * 64 + gB0 * 16 + lrow] = acc2[r];
    g[(gA1 * 16 + row) * 64 + gB1 * 16 + lrow] = acc3[r];
  }
}

// ---------------- K1b: tree-reduce the PB partials -> G[b][4096] ----------------
__global__ __launch_bounds__(256) void reduce_kernel(const float* __restrict__ Gc,
                                                     float* __restrict__ G) {
  __shared__ float s[4][64];
  const int b = blockIdx.y;
  const int g = blockIdx.x;
  const int t = threadIdx.x;
  const int e = g * 64 + (t & 63);
  const int chunk = t >> 6;
  float sum = 0.f;
  for (int p = chunk; p < PB; p += 4)
    sum += Gc[((size_t)b * PB + p) * 4096 + e];
  s[chunk][t & 63] = sum;
  __syncthreads();
  if (t < 64) G[(size_t)b * 4096 + g * 64 + t] = s[0][t] + s[1][t] + s[2][t] + s[3][t];
}

// ---------------- K2: all attention math on 64x64 matrices ----------------
__global__ __launch_bounds__(256) void attn_kernel(const float* __restrict__ G,
    const float* __restrict__ Wq, const float* __restrict__ Wk,
    const float* __restrict__ Wv, const float* __restrict__ Wp,
    const float* __restrict__ rescale, float* __restrict__ E) {
  __shared__ float Gs[4096], GQt[4096], GKt[4096], T[4096];
  __shared__ float attnw[64][DH];
  __shared__ float nq[64], nk[64];
  const int b = blockIdx.x;
  const int t = threadIdx.x;

  for (int i = t; i < 4096; i += 256) Gs[i] = G[(size_t)b * 4096 + i];
  __syncthreads();
  for (int i = t; i < 4096; i += 256) {
    const int c = i >> 6, e = i & 63;
    float sq_ = 0.f, sk_ = 0.f;
    for (int c2 = 0; c2 < 64; ++c2) {
      const float g = Gs[c * 64 + c2];
      sq_ += g * Wq[e * 64 + c2];
      sk_ += g * Wk[e * 64 + c2];
    }
    GQt[c * 64 + e] = sq_;
    GKt[c * 64 + e] = sk_;
  }
  __syncthreads();
  if (t < 64) {
    float s = 0.f;
    for (int c2 = 0; c2 < 64; ++c2) s += Wq[t * 64 + c2] * GQt[c2 * 64 + t];
    nq[t] = sqrtf(fmaxf(s, 0.f));
  } else if (t < 128) {
    const int d = t - 64;
    float s = 0.f;
    for (int c2 = 0; c2 < 64; ++c2) s += Wk[d * 64 + c2] * GKt[c2 * 64 + d];
    nk[d] = sqrtf(fmaxf(s, 0.f));
  }
  __syncthreads();
  if (t < 64) {
    const int h = t >> 4;
    const float rs = rescale[h];
    const float nkd = fmaxf(nk[t], EPS);
    float logits[DH];
    float mx = -1e30f;
    for (int ee = 0; ee < DH; ++ee) {
      const int e = h * DH + ee;
      float num = 0.f;
      for (int c2 = 0; c2 < 64; ++c2) num += Wk[t * 64 + c2] * GQt[c2 * 64 + e];
      const float l = num / (nkd * fmaxf(nq[e], EPS)) * rs;
      logits[ee] = l;
      mx = fmaxf(mx, l);
    }
    float sum = 0.f;
    for (int ee = 0; ee < DH; ++ee) { const float p = expf(logits[ee] - mx); logits[ee] = p; sum += p; }
    const float inv = 1.f / sum;
    for (int ee = 0; ee < DH; ++ee) attnw[t][ee] = logits[ee] * inv;
  }
  __syncthreads();
  for (int i = t; i < 4096; i += 256) {
    const int r = i >> 6, c = i & 63;
    const int h = r >> 4;
    float s = 0.f;
    for (int e = 0; e < DH; ++e) s += attnw[r][e] * Wv[(h * DH + e) * 64 + c];
    T[i] = s;
  }
  __syncthreads();
  for (int i = t; i < 4096; i += 256) {
    const int r = i >> 6, c = i & 63;
    float s = (r == c) ? 1.f : 0.f;
    for (int m = 0; m < 64; ++m) s += Wp[r * 64 + m] * T[m * 64 + c];
    E[(size_t)b * 4096 + i] = s;
  }
}

// ---------------- K3: out = E * x + bp  (E already includes +I) ----------------
__global__ __launch_bounds__(256, 2) void apply_kernel(const float* __restrict__ x,
    const float* __restrict__ E, const float* __restrict__ bp,
    float* __restrict__ out) {
  __shared__ float xt[C * 128];
  __shared__ float Mt[C * 68];   // Mt[k][c] = M[c][k], stride 68
  const int blk = blockIdx.x;
  const int b = blk >> 9;
  const int chunk = blk & 511;
  const float* xb = x + (size_t)b * C * NN;
  float* ob = out + (size_t)b * C * NN;
  const int t = threadIdx.x;
  const int wid = t >> 6, lane = t & 63;
  const int ly = lane >> 3, lx = lane & 7;

  for (int i = t; i < 4096; i += 256) {
    const int k = i >> 6, c = i & 63;
    Mt[k * 68 + c] = E[(size_t)b * 4096 + c * 64 + k];
  }

  for (int tile = 0; tile < 4; ++tile) {
    const int j0 = chunk * 512 + tile * 128;
    __syncthreads();
#pragma unroll
    for (int i = 0; i < 8; ++i) {
      const int idx = i * 256 + t;
      const int c = idx >> 5, jq = idx & 31;
      const float4 v = *reinterpret_cast<const float4*>(xb + (size_t)c * NN + j0 + jq * 4);
      const int sq = jq ^ ((c >> 3) & 7);
      *reinterpret_cast<float4*>(&xt[c * 128 + sq * 4]) = v;
    }
    __syncthreads();
    const int qL = wid * 8 + lx;
    float acc[8][4];
#pragma unroll
    for (int a = 0; a < 8; ++a)
#pragma unroll
      for (int r = 0; r < 4; ++r) acc[a][r] = 0.f;
#pragma unroll 4
    for (int k = 0; k < 64; ++k) {
      const float4 m0 = *reinterpret_cast<const float4*>(&Mt[k * 68 + ly * 8]);
      const float4 m1 = *reinterpret_cast<const float4*>(&Mt[k * 68 + ly * 8 + 4]);
      const float4 xv = *reinterpret_cast<const float4*>(&xt[k * 128 + ((qL ^ ((k >> 3) & 7)) << 2)]);
      const float mv[8] = {m0.x, m0.y, m0.z, m0.w, m1.x, m1.y, m1.z, m1.w};
#pragma unroll
      for (int a = 0; a < 8; ++a) {
        acc[a][0] += mv[a] * xv.x;
        acc[a][1] += mv[a] * xv.y;
        acc[a][2] += mv[a] * xv.z;
        acc[a][3] += mv[a] * xv.w;
      }
    }
#pragma unroll
    for (int a = 0; a < 8; ++a) {
      const int c1 = ly * 8 + a;
      const float bias = bp[c1];
      float4 o4;
      o4.x = acc[a][0] + bias;
      o4.y = acc[a][1] + bias;
      o4.z = acc[a][2] + bias;
      o4.w = acc[a][3] + bias;
      *reinterpret_cast<float4*>(&ob[(size_t)c1 * NN + j0 + qL * 4]) = o4;
    }
  }
}

extern "C" void kernel_launch(void* const* d_in, const int* in_sizes, int n_in,
                              void* d_out, int out_size, void* d_ws, size_t ws_size,
                              hipStream_t stream) {
  const float* x       = (const float*)d_in[0];
  const float* Wq      = (const float*)d_in[1];
  const float* Wk      = (const float*)d_in[2];
  const float* Wv      = (const float*)d_in[3];
  const float* Wp      = (const float*)d_in[4];
  const float* bp      = (const float*)d_in[5];
  const float* rescale = (const float*)d_in[6];
  float* out = (float*)d_out;

  // Partial Grams live in d_out (16 MB of 128 MB) — apply fully overwrites
  // d_out afterwards; reduce reads them before apply runs (stream-ordered).
  float* Gc = out;
  float* G  = (float*)d_ws;              // NB*4096 floats
  float* E  = G + (size_t)NB * 4096;     // NB*4096 floats

  gram_kernel<<<dim3(PB, NB), dim3(256), 0, stream>>>(x, Gc);
  reduce_kernel<<<dim3(64, NB), dim3(256), 0, stream>>>(Gc, G);
  attn_kernel<<<dim3(NB), dim3(256), 0, stream>>>(G, Wq, Wk, Wv, Wp, rescale, E);
  apply_kernel<<<dim3(1024), dim3(256), 0, stream>>>(x, E, bp, out);
}

// Round 5
// 155.716 us; speedup vs baseline: 9.2120x; 1.1660x over previous
//
#include <hip/hip_runtime.h>
#include <math.h>

#define C 64
#define NHEADS 4
#define DH 16
#define NN 262144   // H*W
#define NB 2
#define PB 512      // partial Gram blocks per batch
#define NT 2        // 256-col tiles per block (gram)
#define EPS 1e-12f

typedef __attribute__((ext_vector_type(8))) short short8v;     // 8 bf16
typedef __attribute__((ext_vector_type(8))) unsigned short ushort8v;
typedef __attribute__((ext_vector_type(4))) unsigned short ushort4v;
typedef __attribute__((ext_vector_type(4))) float f32x4;

static __device__ __forceinline__ unsigned short f2bf(float f) {
  union { float f; unsigned int u; } v; v.f = f;
  unsigned int r = v.u + 0x7fffu + ((v.u >> 16) & 1u);   // RNE round to bf16
  return (unsigned short)(r >> 16);
}

// ---------------- K1: per-batch partial Gram via MFMA ----------------
// grid (PB, NB), 256 threads = 4 waves. Block covers NT*256 n-cols.
// LDS tile: bf16 [64][256], 16B slot s of row c stored at (s ^ (c&7)).
__global__ __launch_bounds__(256, 2) void gram_kernel(const float* __restrict__ x,
                                                      float* __restrict__ Gc) {
  __shared__ unsigned short xs[C * 256];
  const int b = blockIdx.y;
  const int chunk = blockIdx.x;
  const float* xb = x + (size_t)b * C * NN;
  const int t = threadIdx.x;
  const int w = t >> 6, l = t & 63;
  const int lrow = l & 15, lhi = l >> 4;

  const int gA0 = (w >> 1) * 2, gA1 = gA0 + 1;
  const int gB0 = (w & 1) * 2,  gB1 = gB0 + 1;
  const int cA0 = gA0 * 16 + lrow, cA1 = gA1 * 16 + lrow;
  const int cB0 = gB0 * 16 + lrow, cB1 = gB1 * 16 + lrow;

  f32x4 acc0 = {0.f,0.f,0.f,0.f}, acc1 = {0.f,0.f,0.f,0.f};
  f32x4 acc2 = {0.f,0.f,0.f,0.f}, acc3 = {0.f,0.f,0.f,0.f};

  for (int tile = 0; tile < NT; ++tile) {
    const int j0 = (chunk * NT + tile) * 256;
    __syncthreads();
#pragma unroll
    for (int i = 0; i < 8; ++i) {
      const int oi = i * 256 + t;
      const int c = oi >> 5, oct = oi & 31;          // 32 octets (8 bf16) per row
      const float* src = xb + (size_t)c * NN + j0 + oct * 8;
      const float4 v0 = *reinterpret_cast<const float4*>(src);
      const float4 v1 = *reinterpret_cast<const float4*>(src + 4);
      ushort8v pk;
      pk[0] = f2bf(v0.x); pk[1] = f2bf(v0.y); pk[2] = f2bf(v0.z); pk[3] = f2bf(v0.w);
      pk[4] = f2bf(v1.x); pk[5] = f2bf(v1.y); pk[6] = f2bf(v1.z); pk[7] = f2bf(v1.w);
      *reinterpret_cast<ushort8v*>(&xs[c * 256 + ((oct ^ (c & 7)) << 3)]) = pk;
    }
    __syncthreads();
#pragma unroll
    for (int s = 0; s < 8; ++s) {
      const int o = s * 4 + lhi;                     // 16B slot holding k=s*32+lhi*8..+7
      const short8v fA0 = *reinterpret_cast<const short8v*>(&xs[cA0 * 256 + ((o ^ (cA0 & 7)) << 3)]);
      const short8v fA1 = *reinterpret_cast<const short8v*>(&xs[cA1 * 256 + ((o ^ (cA1 & 7)) << 3)]);
      const short8v fB0 = *reinterpret_cast<const short8v*>(&xs[cB0 * 256 + ((o ^ (cB0 & 7)) << 3)]);
      const short8v fB1 = *reinterpret_cast<const short8v*>(&xs[cB1 * 256 + ((o ^ (cB1 & 7)) << 3)]);
      acc0 = __builtin_amdgcn_mfma_f32_16x16x32_bf16(fA0, fB0, acc0, 0, 0, 0);
      acc1 = __builtin_amdgcn_mfma_f32_16x16x32_bf16(fA0, fB1, acc1, 0, 0, 0);
      acc2 = __builtin_amdgcn_mfma_f32_16x16x32_bf16(fA1, fB0, acc2, 0, 0, 0);
      acc3 = __builtin_amdgcn_mfma_f32_16x16x32_bf16(fA1, fB1, acc3, 0, 0, 0);
    }
  }
  // C/D layout: col = lane&15, row = (lane>>4)*4 + reg
  float* g = Gc + ((size_t)b * PB + chunk) * 4096;
#pragma unroll
  for (int r = 0; r < 4; ++r) {
    const int row = lhi * 4 + r;
    g[(gA0 * 16 + row) * 64 + gB0 * 16 + lrow] = acc0[r];
    g[(gA0 * 16 + row) * 64 + gB1 * 16 + lrow] = acc1[r];
    g[(gA1 * 16 + row) * 64 + gB0 * 16 + lrow] = acc2[r];
    g[(gA1 * 16 + row) * 64 + gB1 * 16 + lrow] = acc3[r];
  }
}

// ---------------- K1b: tree-reduce the PB partials -> G[b][4096] ----------------
__global__ __launch_bounds__(256) void reduce_kernel(const float* __restrict__ Gc,
                                                     float* __restrict__ G) {
  __shared__ float s[4][64];
  const int b = blockIdx.y;
  const int g = blockIdx.x;
  const int t = threadIdx.x;
  const int e = g * 64 + (t & 63);
  const int chunk = t >> 6;
  float sum = 0.f;
  for (int p = chunk; p < PB; p += 4)
    sum += Gc[((size_t)b * PB + p) * 4096 + e];
  s[chunk][t & 63] = sum;
  __syncthreads();
  if (t < 64) G[(size_t)b * 4096 + g * 64 + t] = s[0][t] + s[1][t] + s[2][t] + s[3][t];
}

// ---------------- K2: attention math -> E (bf16, includes +I) ----------------
__global__ __launch_bounds__(256) void attn_kernel(const float* __restrict__ G,
    const float* __restrict__ Wq, const float* __restrict__ Wk,
    const float* __restrict__ Wv, const float* __restrict__ Wp,
    const float* __restrict__ rescale, unsigned short* __restrict__ Ebf) {
  __shared__ float Gs[4096], GQt[4096], GKt[4096], T[4096];
  __shared__ float attnw[64][DH];
  __shared__ float nq[64], nk[64];
  const int b = blockIdx.x;
  const int t = threadIdx.x;

  for (int i = t; i < 4096; i += 256) Gs[i] = G[(size_t)b * 4096 + i];
  __syncthreads();
  for (int i = t; i < 4096; i += 256) {
    const int c = i >> 6, e = i & 63;
    float sq_ = 0.f, sk_ = 0.f;
    for (int c2 = 0; c2 < 64; ++c2) {
      const float g = Gs[c * 64 + c2];
      sq_ += g * Wq[e * 64 + c2];
      sk_ += g * Wk[e * 64 + c2];
    }
    GQt[c * 64 + e] = sq_;
    GKt[c * 64 + e] = sk_;
  }
  __syncthreads();
  if (t < 64) {
    float s = 0.f;
    for (int c2 = 0; c2 < 64; ++c2) s += Wq[t * 64 + c2] * GQt[c2 * 64 + t];
    nq[t] = sqrtf(fmaxf(s, 0.f));
  } else if (t < 128) {
    const int d = t - 64;
    float s = 0.f;
    for (int c2 = 0; c2 < 64; ++c2) s += Wk[d * 64 + c2] * GKt[c2 * 64 + d];
    nk[d] = sqrtf(fmaxf(s, 0.f));
  }
  __syncthreads();
  if (t < 64) {
    const int h = t >> 4;
    const float rs = rescale[h];
    const float nkd = fmaxf(nk[t], EPS);
    float logits[DH];
    float mx = -1e30f;
    for (int ee = 0; ee < DH; ++ee) {
      const int e = h * DH + ee;
      float num = 0.f;
      for (int c2 = 0; c2 < 64; ++c2) num += Wk[t * 64 + c2] * GQt[c2 * 64 + e];
      const float l = num / (nkd * fmaxf(nq[e], EPS)) * rs;
      logits[ee] = l;
      mx = fmaxf(mx, l);
    }
    float sum = 0.f;
    for (int ee = 0; ee < DH; ++ee) { const float p = expf(logits[ee] - mx); logits[ee] = p; sum += p; }
    const float inv = 1.f / sum;
    for (int ee = 0; ee < DH; ++ee) attnw[t][ee] = logits[ee] * inv;
  }
  __syncthreads();
  for (int i = t; i < 4096; i += 256) {
    const int r = i >> 6, c = i & 63;
    const int h = r >> 4;
    float s = 0.f;
    for (int e = 0; e < DH; ++e) s += attnw[r][e] * Wv[(h * DH + e) * 64 + c];
    T[i] = s;
  }
  __syncthreads();
  for (int i = t; i < 4096; i += 256) {
    const int r = i >> 6, c = i & 63;
    float s = (r == c) ? 1.f : 0.f;
    for (int m = 0; m < 64; ++m) s += Wp[r * 64 + m] * T[m * 64 + c];
    Ebf[(size_t)b * 4096 + i] = f2bf(s);
  }
}

// ---------------- K3: out = E * x + bp via MFMA ----------------
// grid (2048, NB), 256 threads = 4 waves. Block = 64 o x 128 n output tile.
// LDS: xt[n][c] bf16 transposed (16 KB), 16B block s of row n at (s ^ (n&7)).
// E fragments (A-operand) hoisted to registers from global bf16 E (L2-hot).
__global__ __launch_bounds__(256, 4) void apply_kernel(const float* __restrict__ x,
    const unsigned short* __restrict__ Ebf, const float* __restrict__ bp,
    float* __restrict__ out) {
  __shared__ unsigned short xt[128 * 64];   // [n][c] bf16, swizzled
  const int b = blockIdx.y;
  const int n0 = blockIdx.x * 128;
  const float* xb = x + (size_t)b * C * NN;
  float* ob = out + (size_t)b * C * NN;
  const int t = threadIdx.x;
  const int w = t >> 6, l = t & 63;
  const int lrow = l & 15, lhi = l >> 4;

  // hoist E fragments: ef[ot][ks] = E[ot*16 + lrow][ks*32 + lhi*8 .. +7]
  short8v ef[4][2];
  const unsigned short* eb = Ebf + (size_t)b * 4096;
#pragma unroll
  for (int ot = 0; ot < 4; ++ot)
#pragma unroll
    for (int ks = 0; ks < 2; ++ks)
      ef[ot][ks] = *reinterpret_cast<const short8v*>(eb + (ot * 16 + lrow) * 64 + ks * 32 + lhi * 8);

  // stage x transposed: wave w covers c in [w*16, w*16+16), lane covers n = h*64+l
#pragma unroll
  for (int h = 0; h < 2; ++h) {
    const int n = h * 64 + l;
#pragma unroll
    for (int i = 0; i < 4; ++i) {
      const int c0 = w * 16 + i * 4;
      const float v0 = xb[(size_t)(c0 + 0) * NN + n0 + n];
      const float v1 = xb[(size_t)(c0 + 1) * NN + n0 + n];
      const float v2 = xb[(size_t)(c0 + 2) * NN + n0 + n];
      const float v3 = xb[(size_t)(c0 + 3) * NN + n0 + n];
      ushort4v pk;
      pk[0] = f2bf(v0); pk[1] = f2bf(v1); pk[2] = f2bf(v2); pk[3] = f2bf(v3);
      const int q = c0 >> 2;   // 8B-quad index 0..15
      *reinterpret_cast<ushort4v*>(
          &xt[n * 64 + ((((q >> 1) ^ (n & 7)) << 3) + (q & 1) * 4)]) = pk;
    }
  }
  __syncthreads();

  // MFMA: wave w owns n-range [w*32, w*32+32) = 2 n-tiles; 4 o-tiles each.
  f32x4 acc[4][2];
#pragma unroll
  for (int ot = 0; ot < 4; ++ot)
#pragma unroll
    for (int nn = 0; nn < 2; ++nn) acc[ot][nn] = (f32x4){0.f, 0.f, 0.f, 0.f};

  const int nbase = w * 32;
#pragma unroll
  for (int nn = 0; nn < 2; ++nn) {
    const int n = nbase + nn * 16 + lrow;   // this lane's output col (local)
#pragma unroll
    for (int ks = 0; ks < 2; ++ks) {
      const int s = ks * 4 + lhi;           // logical 16B slot (k = s*8..s*8+7)
      const short8v xf = *reinterpret_cast<const short8v*>(&xt[n * 64 + ((s ^ (n & 7)) << 3)]);
#pragma unroll
      for (int ot = 0; ot < 4; ++ot)
        acc[ot][nn] = __builtin_amdgcn_mfma_f32_16x16x32_bf16(ef[ot][ks], xf, acc[ot][nn], 0, 0, 0);
    }
  }

  // store: row o = ot*16 + lhi*4 + r, col n = nbase + nn*16 + lrow
#pragma unroll
  for (int ot = 0; ot < 4; ++ot) {
#pragma unroll
    for (int r = 0; r < 4; ++r) {
      const int o = ot * 16 + lhi * 4 + r;
      const float bias = bp[o];
#pragma unroll
      for (int nn = 0; nn < 2; ++nn) {
        const int n = nbase + nn * 16 + lrow;
        ob[(size_t)o * NN + n0 + n] = acc[ot][nn][r] + bias;
      }
    }
  }
}

extern "C" void kernel_launch(void* const* d_in, const int* in_sizes, int n_in,
                              void* d_out, int out_size, void* d_ws, size_t ws_size,
                              hipStream_t stream) {
  const float* x       = (const float*)d_in[0];
  const float* Wq      = (const float*)d_in[1];
  const float* Wk      = (const float*)d_in[2];
  const float* Wv      = (const float*)d_in[3];
  const float* Wp      = (const float*)d_in[4];
  const float* bp      = (const float*)d_in[5];
  const float* rescale = (const float*)d_in[6];
  float* out = (float*)d_out;

  // Partial Grams live in d_out (16 MB of 128 MB) — apply fully overwrites
  // d_out afterwards; reduce reads them before apply runs (stream-ordered).
  float* Gc = out;
  float* G  = (float*)d_ws;                          // NB*4096 f32
  unsigned short* Ebf = (unsigned short*)(G + (size_t)NB * 4096);  // NB*4096 bf16

  gram_kernel<<<dim3(PB, NB), dim3(256), 0, stream>>>(x, Gc);
  reduce_kernel<<<dim3(64, NB), dim3(256), 0, stream>>>(Gc, G);
  attn_kernel<<<dim3(NB), dim3(256), 0, stream>>>(G, Wq, Wk, Wv, Wp, rescale, Ebf);
  apply_kernel<<<dim3(2048, NB), dim3(256), 0, stream>>>(x, Ebf, bp, out);
}